// Round 8
// baseline (862.305 us; speedup 1.0000x reference)
//
#include <hip/hip_runtime.h>
#include <math.h>

#define EMB 64
static constexpr float INV_SQRT_DK = 0.17677669529663687f; // 1/sqrt(32)

#define NPART 32          // node-range partitions for the bucket sort
#define NBK 512           // KG counting/bucket blocks
#define NBU 192           // UI counting/bucket blocks
#define P4_KG 1024        // KG scatter blocks (32 slices x 32 partitions)
#define P4_UI 512         // UI scatter blocks (16 slices x 32 partitions)

__device__ inline unsigned short f2bf(float f) {
    union { float f; unsigned u; } v; v.f = f;
    unsigned r = v.u + 0x7FFF + ((v.u >> 16) & 1);   // round-to-nearest-even
    return (unsigned short)(r >> 16);
}
__device__ inline float bfhi(unsigned w) {           // high 16 bits as bf16
    union { float f; unsigned u; } v; v.u = w & 0xFFFF0000u; return v.f;
}
__device__ inline float bflo(unsigned w) {           // low 16 bits as bf16
    union { float f; unsigned u; } v; v.u = w << 16; return v.f;
}
__device__ inline float bf2f(unsigned short b) {
    union { float f; unsigned u; } v; v.u = ((unsigned)b) << 16; return v.f;
}

// ---- proj = e @ W_Q; emit packed (proj<<16|e) and e_bf gather tables ----
__global__ void proj_pack_kernel(const float* __restrict__ e, const float* __restrict__ W,
                                 unsigned* __restrict__ packed,
                                 unsigned short* __restrict__ e_bf, int n) {
    __shared__ float Wl[64 * 64];
    int t = threadIdx.x;
    for (int i = t; i < 64 * 64; i += blockDim.x) Wl[i] = W[i];
    __syncthreads();
    int lane = t & 63;
    int wavesPerBlock = blockDim.x >> 6;
    int wid = blockIdx.x * wavesPerBlock + (t >> 6);
    int nw = gridDim.x * wavesPerBlock;
    for (int r = wid; r < n; r += nw) {
        float x = e[(size_t)r * EMB + lane];
        float acc = 0.f;
#pragma unroll
        for (int k = 0; k < 64; ++k) {
            float ek = __shfl(x, k, 64);
            acc += ek * Wl[k * 64 + lane];
        }
        unsigned pb = f2bf(acc), eb = f2bf(x);
        size_t ix = (size_t)r * EMB + lane;
        packed[ix] = (pb << 16) | eb;
        e_bf[ix] = (unsigned short)eb;
    }
}

// ---------------- P1: per-node histogram + per-(block,partition) counts ----------------
__global__ void __launch_bounds__(256) p1_count_kernel(
        const int* __restrict__ head, int* __restrict__ cnt_h, int E, int shiftH,
        int* __restrict__ cnt2K,
        const int* __restrict__ iu, int* __restrict__ cnt_u, int EI, int shiftU,
        int* __restrict__ cnt2U) {
    __shared__ int lc[NPART];
    int b = blockIdx.x;
    if (threadIdx.x < NPART) lc[threadIdx.x] = 0;
    __syncthreads();
    if (b < NBK) {
        int chunk = (E + NBK - 1) / NBK;
        int lo = b * chunk, hi = min(lo + chunk, E);
        for (int e = lo + (int)threadIdx.x; e < hi; e += 256) {
            int h = head[e];
            atomicAdd(&cnt_h[h], 1);
            atomicAdd(&lc[h >> shiftH], 1);
        }
        __syncthreads();
        if (threadIdx.x < NPART) cnt2K[threadIdx.x * NBK + b] = lc[threadIdx.x];
    } else {
        int bb = b - NBK;
        int chunk = (EI + NBU - 1) / NBU;
        int lo = bb * chunk, hi = min(lo + chunk, EI);
        for (int e = lo + (int)threadIdx.x; e < hi; e += 256) {
            int u = iu[e];
            atomicAdd(&cnt_u[u], 1);
            atomicAdd(&lc[u >> shiftU], 1);
        }
        __syncthreads();
        if (threadIdx.x < NPART) cnt2U[threadIdx.x * NBU + bb] = lc[threadIdx.x];
    }
}

// ---------------- multi-block exclusive scan of node degrees (3 phases) ----------------
__global__ void scan_partial_both(const int* __restrict__ degH, int* __restrict__ partH,
                                  int nH, int nbH,
                                  const int* __restrict__ degU, int* __restrict__ partU, int nU) {
    bool isU = (int)blockIdx.x >= nbH;
    const int* deg = isU ? degU : degH;
    int* part = isU ? partU : partH;
    int n = isU ? nU : nH;
    int b = isU ? blockIdx.x - nbH : blockIdx.x;
    int t = threadIdx.x;             // 256 threads, 4 elems each
    int i0 = b * 1024 + t * 4;
    int s = 0;
#pragma unroll
    for (int k = 0; k < 4; ++k) { int id = i0 + k; if (id < n) s += deg[id]; }
#pragma unroll
    for (int m = 1; m <= 32; m <<= 1) s += __shfl_xor(s, m, 64);
    __shared__ int wsum[4];
    if ((t & 63) == 0) wsum[t >> 6] = s;
    __syncthreads();
    if (t == 0) part[b] = wsum[0] + wsum[1] + wsum[2] + wsum[3];
}

__global__ void scan_block_both(int* __restrict__ partH, int nbH,
                                int* __restrict__ partU, int nbU) {
    __shared__ int sh[256];
    int t = threadIdx.x;
    for (int pass = 0; pass < 2; ++pass) {
        int* part = pass ? partU : partH;
        int nb = pass ? nbU : nbH;
        int v = (t < nb) ? part[t] : 0;
        sh[t] = v;
        __syncthreads();
        for (int d = 1; d < 256; d <<= 1) {
            int x = (t >= d) ? sh[t - d] : 0;
            __syncthreads();
            sh[t] += x;
            __syncthreads();
        }
        if (t < nb) part[t] = sh[t] - v; // exclusive
        __syncthreads();
    }
}

// writes both off[] and cur[] (fill cursor)
__global__ void scan_final_both(const int* __restrict__ degH, const int* __restrict__ partH,
                                int* __restrict__ offH, int* __restrict__ curH,
                                int nH, int nbH, int totalH,
                                const int* __restrict__ degU, const int* __restrict__ partU,
                                int* __restrict__ offU, int* __restrict__ curU,
                                int nU, int totalU) {
    bool isU = (int)blockIdx.x >= nbH;
    const int* deg = isU ? degU : degH;
    const int* part = isU ? partU : partH;
    int* off = isU ? offU : offH;
    int* cur = isU ? curU : curH;
    int n = isU ? nU : nH;
    int total = isU ? totalU : totalH;
    int b = isU ? blockIdx.x - nbH : blockIdx.x;
    int t = threadIdx.x;
    int lane = t & 63, w = t >> 6;
    int i0 = b * 1024 + t * 4;
    int v[4]; int s = 0;
#pragma unroll
    for (int k = 0; k < 4; ++k) { int id = i0 + k; v[k] = (id < n) ? deg[id] : 0; s += v[k]; }
    int incl = s;
#pragma unroll
    for (int d = 1; d < 64; d <<= 1) { int x = __shfl_up(incl, d, 64); if (lane >= d) incl += x; }
    __shared__ int wsum[4];
    if (lane == 63) wsum[w] = incl;
    __syncthreads();
    int woff = 0;
    for (int i = 0; i < w; ++i) woff += wsum[i];
    int excl = incl - s + woff + part[b];
#pragma unroll
    for (int k = 0; k < 4; ++k) {
        int id = i0 + k;
        if (id < n) { off[id] = excl; cur[id] = excl; }
        excl += v[k];
    }
    if (b == 0 && t == 0) off[n] = total;
}

// ---------------- scan of the (partition-major) bucket counts ----------------
__device__ void block_exscan_1024(int* __restrict__ arr, int n) {
    __shared__ int part[1024];
    int t = threadIdx.x;
    int per = (n + 1023) >> 10;
    int base = t * per;
    int s = 0;
    for (int i = 0; i < per; ++i) { int id = base + i; if (id < n) s += arr[id]; }
    part[t] = s;
    __syncthreads();
    for (int d = 1; d < 1024; d <<= 1) {
        int v = (t >= d) ? part[t - d] : 0;
        __syncthreads();
        part[t] += v;
        __syncthreads();
    }
    int pre = t ? part[t - 1] : 0;
    for (int i = 0; i < per; ++i) {
        int id = base + i;
        if (id < n) { int v = arr[id]; arr[id] = pre; pre += v; }
    }
    __syncthreads();
}
__global__ void scan2_kernel(int* __restrict__ cnt2K, int nK, int* __restrict__ cnt2U, int nU) {
    block_exscan_1024(cnt2K, nK);
    block_exscan_1024(cnt2U, nU);
}

// ---------------- P3: dense bucket write (counting sort by partition) ----------------
__global__ void __launch_bounds__(256) p3_bucket_kernel(
        const int* __restrict__ head, const int* __restrict__ tail,
        const int* __restrict__ etype, int E, int shiftH,
        const int* __restrict__ cnt2K, uint2* __restrict__ bktK,
        const int* __restrict__ iu, const int* __restrict__ ii,
        const float* __restrict__ w, int EI, int shiftU,
        const int* __restrict__ cnt2U, uint2* __restrict__ bktU) {
    __shared__ int lcur[NPART];
    int b = blockIdx.x;
    if (b < NBK) {
        if (threadIdx.x < NPART) lcur[threadIdx.x] = cnt2K[threadIdx.x * NBK + b];
        __syncthreads();
        int chunk = (E + NBK - 1) / NBK;
        int lo = b * chunk, hi = min(lo + chunk, E);
        for (int e = lo + (int)threadIdx.x; e < hi; e += 256) {
            int h = head[e];
            int pos = atomicAdd(&lcur[h >> shiftH], 1);
            bktK[pos] = make_uint2((unsigned)(tail[e] | ((etype[e] - 1) << 17)), (unsigned)h);
        }
    } else {
        int bb = b - NBK;
        if (threadIdx.x < NPART) lcur[threadIdx.x] = cnt2U[threadIdx.x * NBU + bb];
        __syncthreads();
        int chunk = (EI + NBU - 1) / NBU;
        int lo = bb * chunk, hi = min(lo + chunk, EI);
        for (int e = lo + (int)threadIdx.x; e < hi; e += 256) {
            int u = iu[e];
            int pos = atomicAdd(&lcur[u >> shiftU], 1);
            unsigned wq = (unsigned)(w[e] * 32767.f + 0.5f);
            bktU[pos] = make_uint2((unsigned)ii[e] | (wq << 17), (unsigned)u);
        }
    }
}

// ---------------- P4: partition-local scatter into CSR col ----------------
// partition p = blockIdx % 32 (keeps p%8 XCD-aligned under round-robin);
// each partition's bucket (~1 MB) + col region (~0.4 MB) is L2-resident.
__global__ void __launch_bounds__(256) p4_fill_kernel(
        const uint2* __restrict__ bktK, const int* __restrict__ cnt2K, int E,
        int* __restrict__ cur_h, int* __restrict__ col_h,
        const uint2* __restrict__ bktU, const int* __restrict__ cnt2U, int EI,
        int* __restrict__ cur_u, unsigned* __restrict__ col_ui) {
    int b = blockIdx.x;
    if (b < P4_KG) {
        int p = b & (NPART - 1), s = b >> 5;            // 32 slices per partition
        int st = cnt2K[p * NBK];
        int en = (p == NPART - 1) ? E : cnt2K[(p + 1) * NBK];
        long long len = en - st;
        int lo = st + (int)(len * s / 32);
        int hi = st + (int)(len * (s + 1) / 32);
        for (int i = lo + (int)threadIdx.x; i < hi; i += 256) {
            uint2 r = bktK[i];
            int pos = atomicAdd(&cur_h[r.y], 1);
            col_h[pos] = (int)r.x;
        }
    } else {
        int bb = b - P4_KG;
        int p = bb & (NPART - 1), s = bb >> 5;          // 16 slices per partition
        int st = cnt2U[p * NBU];
        int en = (p == NPART - 1) ? EI : cnt2U[(p + 1) * NBU];
        long long len = en - st;
        int lo = st + (int)(len * s / 16);
        int hi = st + (int)(len * (s + 1) / 16);
        for (int i = lo + (int)threadIdx.x; i < hi; i += 256) {
            uint2 r = bktU[i];
            int pos = atomicAdd(&cur_u[r.y], 1);
            col_ui[pos] = r.x;
        }
    }
}

// ------- fused agg: KG = 2 dims/lane, 2 edges/wave;  UI = per-user weighted agg -------
#define KG_PAIR(J, P, W) {                                                  \
        int rr = (P) >> 17;                                                 \
        float rl0 = relS[rr * EMB + dd], rl1 = relS[rr * EMB + dd + 1];     \
        float pt0 = bfhi(W.x), pt1 = bfhi(W.y);                             \
        float et0 = bflo(W.x), et1 = bflo(W.y);                             \
        float prod = fmaf(q0 * rl0, pt0, q1 * rl1 * pt1);                   \
        prod += __shfl_xor(prod, 1, 64);                                    \
        prod += __shfl_xor(prod, 2, 64);                                    \
        prod += __shfl_xor(prod, 4, 64);                                    \
        prod += __shfl_xor(prod, 8, 64);                                    \
        float ex = __expf(prod * INV_SQRT_DK);                              \
        if ((J) + half >= e) ex = 0.f;                                      \
        den += ex;                                                          \
        num0 = fmaf(ex * rl0, et0, num0);                                   \
        num1 = fmaf(ex * rl1, et1, num1); }

template <bool HOP1>
__global__ void agg_fused_kernel(const unsigned* __restrict__ packed,
                                 const unsigned short* __restrict__ e_bf,
                                 const float* __restrict__ rel_emb,
                                 const int* __restrict__ off_h, const int* __restrict__ col_h,
                                 const int* __restrict__ off_u,
                                 const unsigned* __restrict__ col_ui,
                                 const float* __restrict__ e_base, float* __restrict__ e_cur,
                                 float* __restrict__ e_res, int n_ent,
                                 const float* __restrict__ u_base, float* __restrict__ u_res,
                                 int n_usr, int kgBlocks, int totalBlocks) {
    __shared__ float relS[16 * EMB];
    int bid = blockIdx.x;
    // Bresenham interleave of kg-role and ui-role blocks
    size_t lo = (size_t)bid * kgBlocks / totalBlocks;
    size_t hi = (size_t)(bid + 1) * kgBlocks / totalBlocks;
    int lane = threadIdx.x & 63;
    int wslot = threadIdx.x >> 6;

    if (hi > lo) {
        // ---------------- KG entity block: 2 dims/lane, 2 edges/wave ----------------
        for (int i = threadIdx.x; i < 16 * EMB; i += blockDim.x) relS[i] = rel_emb[i];
        __syncthreads();
        int wid = (int)lo * 4 + wslot;
        if (wid >= n_ent) return;
        int s = off_h[wid], e = off_h[wid + 1];
        int half = lane >> 5;
        int sub  = lane & 31;
        int dd   = sub * 2;
        uint2 qw = *(const uint2*)&packed[(size_t)wid * EMB + dd];
        float q0 = bfhi(qw.x), q1 = bfhi(qw.y);
        float num0 = 0.f, num1 = 0.f, den = 0.f;
        int j = s;
        for (; j + 3 < e; j += 4) {           // 2 pairs (4 edges), no dummies possible
            int pA = col_h[j + half];
            int pB = col_h[j + 2 + half];
            uint2 wA = *(const uint2*)&packed[(size_t)(pA & 131071) * EMB + dd];
            uint2 wB = *(const uint2*)&packed[(size_t)(pB & 131071) * EMB + dd];
            KG_PAIR(j, pA, wA);
            KG_PAIR(j + 2, pB, wB);
        }
        for (; j < e; j += 2) {               // remainder pair, may have a dummy lane-half
            int jj = j + half; if (jj >= e) jj = e - 1;
            int pA = col_h[jj];
            uint2 wA = *(const uint2*)&packed[(size_t)(pA & 131071) * EMB + dd];
            KG_PAIR(j, pA, wA);
        }
        // combine the two edge-halves (once per node)
        den  += __shfl_xor(den, 32, 64);
        num0 += __shfl_xor(num0, 32, 64);
        num1 += __shfl_xor(num1, 32, 64);
        float inv = (e > s) ? 1.f / den : 0.f;   // deferred softmax division
        float v0 = num0 * inv, v1 = num1 * inv;
        float ss = fmaf(v0, v0, v1 * v1);
#pragma unroll
        for (int m = 1; m <= 16; m <<= 1) ss += __shfl_xor(ss, m, 64);
        float rn = 1.f / fmaxf(sqrtf(ss), 1e-12f);
        float o0 = v0 * rn, o1 = v1 * rn;
        if (half == 0) {
            float2* res2 = (float2*)&e_res[(size_t)wid * EMB + dd];
            if (HOP1) {
                *(float2*)&e_cur[(size_t)wid * EMB + dd] = make_float2(o0, o1);
                const float2 b = *(const float2*)&e_base[(size_t)wid * EMB + dd];
                *res2 = make_float2(b.x + o0, b.y + o1);
            } else {
                float2 rv = *res2;
                *res2 = make_float2(rv.x + o0, rv.y + o1);
            }
        }
    } else {
        // ---------------- UI user block ----------------
        int wid = (bid - (int)lo) * 4 + wslot;
        if (wid >= n_usr) return;
        int s = off_u[wid], e = off_u[wid + 1];
        float acc = 0.f;
        int j = s;
        for (; j + 3 < e; j += 4) {
            unsigned c0 = col_ui[j],     c1 = col_ui[j + 1];
            unsigned c2 = col_ui[j + 2], c3 = col_ui[j + 3];
            float w0 = (c0 >> 17) * (1.f / 32767.f);
            float w1 = (c1 >> 17) * (1.f / 32767.f);
            float w2 = (c2 >> 17) * (1.f / 32767.f);
            float w3 = (c3 >> 17) * (1.f / 32767.f);
            float v0 = bf2f(e_bf[(size_t)(c0 & 131071u) * EMB + lane]);
            float v1 = bf2f(e_bf[(size_t)(c1 & 131071u) * EMB + lane]);
            float v2 = bf2f(e_bf[(size_t)(c2 & 131071u) * EMB + lane]);
            float v3 = bf2f(e_bf[(size_t)(c3 & 131071u) * EMB + lane]);
            acc = fmaf(w0, v0, acc);
            acc = fmaf(w1, v1, acc);
            acc = fmaf(w2, v2, acc);
            acc = fmaf(w3, v3, acc);
        }
        for (; j < e; ++j) {
            unsigned c = col_ui[j];
            acc = fmaf((c >> 17) * (1.f / 32767.f),
                       bf2f(e_bf[(size_t)(c & 131071u) * EMB + lane]), acc);
        }
        float ss = acc * acc;
#pragma unroll
        for (int m = 1; m <= 32; m <<= 1) ss += __shfl_xor(ss, m, 64);
        float o = acc / fmaxf(sqrtf(ss), 1e-12f);
        size_t ix = (size_t)wid * EMB + lane;
        if (HOP1) u_res[ix] = u_base[ix] + o;
        else      u_res[ix] += o;
    }
}

extern "C" void kernel_launch(void* const* d_in, const int* in_sizes, int n_in,
                              void* d_out, int out_size, void* d_ws, size_t ws_size,
                              hipStream_t stream) {
    const float* user_emb   = (const float*)d_in[0];
    const float* entity_emb = (const float*)d_in[1];
    const int*   edge_index = (const int*)d_in[2];   // [2, E]
    const int*   edge_type  = (const int*)d_in[3];   // [E]
    const int*   inter_edge = (const int*)d_in[4];   // [2, EI]
    const float* inter_w    = (const float*)d_in[5]; // [EI]
    const float* W_Q        = (const float*)d_in[6]; // [64,64]
    const float* rel_emb    = (const float*)d_in[7]; // [16,64]

    const int E     = in_sizes[3];
    const int EI    = in_sizes[5];
    const int n_ent = in_sizes[1] / EMB;
    const int n_usr = in_sizes[0] / EMB;

    const int* head = edge_index;
    const int* tail = edge_index + E;
    const int* iu   = inter_edge;
    const int* ii   = inter_edge + EI;

    // partition shifts: smallest shift with <= NPART partitions
    int shiftH = 0; while (((n_ent + (1 << shiftH) - 1) >> shiftH) > NPART) ++shiftH;
    int shiftU = 0; while (((n_usr + (1 << shiftU) - 1) >> shiftU) > NPART) ++shiftU;

    // ---- workspace layout ----
    char* ws = (char*)d_ws;
    unsigned* packed        = (unsigned*)ws;        ws += (size_t)n_ent * EMB * 4;
    unsigned short* e_bf    = (unsigned short*)ws;  ws += (size_t)n_ent * EMB * 2;
    float* e_cur = (float*)ws;                 ws += (size_t)n_ent * EMB * 4;
    int*      col_h  = (int*)ws;               ws += (size_t)E * 4;
    unsigned* col_ui = (unsigned*)ws;          ws += (size_t)EI * 4;
    int*   off_h = (int*)ws;                   ws += (size_t)(n_ent + 1) * 4;
    int*   off_u = (int*)ws;                   ws += (size_t)(n_usr + 1) * 4;
    int*   cur_h = (int*)ws;                   ws += (size_t)n_ent * 4;   // cur_h|cur_u adjacent
    int*   cur_u = (int*)ws;                   ws += (size_t)n_usr * 4;
    int*   partH = (int*)ws;                   ws += 256 * 4;
    int*   partU = (int*)ws;                   ws += 256 * 4;
    int*   cnt2K = (int*)ws;                   ws += (size_t)NPART * NBK * 4;
    int*   cnt2U = (int*)ws;                   ws += (size_t)NPART * NBU * 4;
    // buckets overlay packed/e_bf (dead until proj_pack runs, after CSR build)
    uint2* bktK = (uint2*)packed;              // E * 8 bytes
    uint2* bktU = bktK + E;                    // EI * 8 bytes  (fits in 38.4 MB region)

    float* e_res = (float*)d_out;
    float* u_res = e_res + (size_t)n_ent * EMB;

    const int nbH = (n_ent + 1023) / 1024;     // 98  (<=256)
    const int nbU = (n_usr + 1023) / 1024;     // 49  (<=256)

    // ---- CSR build via partition counting-sort (once; reused by both hops) ----
    hipMemsetAsync(cur_h, 0, (size_t)(n_ent + n_usr) * 4, stream);
    p1_count_kernel<<<NBK + NBU, 256, 0, stream>>>(head, cur_h, E, shiftH, cnt2K,
                                                   iu, cur_u, EI, shiftU, cnt2U);
    scan_partial_both<<<nbH + nbU, 256, 0, stream>>>(cur_h, partH, n_ent, nbH, cur_u, partU, n_usr);
    scan_block_both<<<1, 256, 0, stream>>>(partH, nbH, partU, nbU);
    scan_final_both<<<nbH + nbU, 256, 0, stream>>>(cur_h, partH, off_h, cur_h, n_ent, nbH, E,
                                                   cur_u, partU, off_u, cur_u, n_usr, EI);
    scan2_kernel<<<1, 1024, 0, stream>>>(cnt2K, NPART * NBK, cnt2U, NPART * NBU);
    p3_bucket_kernel<<<NBK + NBU, 256, 0, stream>>>(head, tail, edge_type, E, shiftH, cnt2K, bktK,
                                                    iu, ii, inter_w, EI, shiftU, cnt2U, bktU);
    p4_fill_kernel<<<P4_KG + P4_UI, 256, 0, stream>>>(bktK, cnt2K, E, cur_h, col_h,
                                                      bktU, cnt2U, EI, cur_u, col_ui);

    const int kgBlocks = (n_ent + 3) / 4;
    const int uiBlocks = (n_usr + 3) / 4;
    const int totalBlocks = kgBlocks + uiBlocks;

    // ---- hop 1 (e_in = entity_emb) ----
    proj_pack_kernel<<<kgBlocks, 256, 0, stream>>>(entity_emb, W_Q, packed, e_bf, n_ent);
    agg_fused_kernel<true><<<totalBlocks, 256, 0, stream>>>(
        packed, e_bf, rel_emb, off_h, col_h, off_u, col_ui,
        entity_emb, e_cur, e_res, n_ent, user_emb, u_res, n_usr, kgBlocks, totalBlocks);

    // ---- hop 2 (e_in = e_cur) ----
    proj_pack_kernel<<<kgBlocks, 256, 0, stream>>>(e_cur, W_Q, packed, e_bf, n_ent);
    agg_fused_kernel<false><<<totalBlocks, 256, 0, stream>>>(
        packed, e_bf, rel_emb, off_h, col_h, off_u, col_ui,
        nullptr, nullptr, e_res, n_ent, nullptr, u_res, n_usr, kgBlocks, totalBlocks);
}

// Round 9
// 730.218 us; speedup vs baseline: 1.1809x; 1.1809x over previous
//
#include <hip/hip_runtime.h>
#include <math.h>

#define EMB 64
static constexpr float INV_SQRT_DK = 0.17677669529663687f; // 1/sqrt(32)

#define NPART 32          // node-range partitions for the bucket sort
#define NBK 512           // KG bucket blocks
#define NBU 192           // UI bucket blocks
#define P4_KG 1024        // KG scatter blocks (32 slices x 32 partitions)
#define P4_UI 512         // UI scatter blocks (16 slices x 32 partitions)
#define P4T   (P4_KG + P4_UI)
#define PROJ_MERGED 1536  // proj-role blocks inside the merged p4 kernel
#define PROJ2_BLOCKS 2048

__device__ inline unsigned short f2bf(float f) {
    union { float f; unsigned u; } v; v.f = f;
    unsigned r = v.u + 0x7FFF + ((v.u >> 16) & 1);   // round-to-nearest-even
    return (unsigned short)(r >> 16);
}
__device__ inline float bfhi(unsigned w) {           // high 16 bits as bf16
    union { float f; unsigned u; } v; v.u = w & 0xFFFF0000u; return v.f;
}
__device__ inline float bflo(unsigned w) {           // low 16 bits as bf16
    union { float f; unsigned u; } v; v.u = w << 16; return v.f;
}

// ---- proj rows: packed[r] = (bf16(e@W) << 16) | bf16(e), grid-stride ----
__device__ inline void proj_rows(const float* __restrict__ e, const float* __restrict__ Wl,
                                 unsigned* __restrict__ packed, int n, int wid, int nw, int lane) {
    for (int r = wid; r < n; r += nw) {
        float x = e[(size_t)r * EMB + lane];
        float acc = 0.f;
#pragma unroll
        for (int k = 0; k < 64; ++k) {
            float ek = __shfl(x, k, 64);
            acc += ek * Wl[k * 64 + lane];
        }
        packed[(size_t)r * EMB + lane] = (((unsigned)f2bf(acc)) << 16) | f2bf(x);
    }
}

__global__ void __launch_bounds__(256) proj_pack_kernel(
        const float* __restrict__ e, const float* __restrict__ W,
        unsigned* __restrict__ packed, int n) {
    __shared__ float Wl[64 * 64];
    for (int i = threadIdx.x; i < 64 * 64; i += blockDim.x) Wl[i] = W[i];
    __syncthreads();
    int lane = threadIdx.x & 63;
    int wid = blockIdx.x * 4 + (threadIdx.x >> 6);
    proj_rows(e, Wl, packed, n, wid, gridDim.x * 4, lane);
}

// ---------------- P1: per-node histogram only ----------------
__global__ void p1_hist(const int* __restrict__ head, int* __restrict__ cnt_h, int E,
                        const int* __restrict__ iu, int* __restrict__ cnt_u, int EI) {
    int i = blockIdx.x * blockDim.x + threadIdx.x;
    if (i < E) atomicAdd(&cnt_h[head[i]], 1);
    else if (i < E + EI) atomicAdd(&cnt_u[iu[i - E]], 1);
}

// ---------------- multi-block exclusive scan of node degrees (3 phases) ----------------
__global__ void scan_partial_both(const int* __restrict__ degH, int* __restrict__ partH,
                                  int nH, int nbH,
                                  const int* __restrict__ degU, int* __restrict__ partU, int nU) {
    bool isU = (int)blockIdx.x >= nbH;
    const int* deg = isU ? degU : degH;
    int* part = isU ? partU : partH;
    int n = isU ? nU : nH;
    int b = isU ? blockIdx.x - nbH : blockIdx.x;
    int t = threadIdx.x;             // 256 threads, 4 elems each
    int i0 = b * 1024 + t * 4;
    int s = 0;
#pragma unroll
    for (int k = 0; k < 4; ++k) { int id = i0 + k; if (id < n) s += deg[id]; }
#pragma unroll
    for (int m = 1; m <= 32; m <<= 1) s += __shfl_xor(s, m, 64);
    __shared__ int wsum[4];
    if ((t & 63) == 0) wsum[t >> 6] = s;
    __syncthreads();
    if (t == 0) part[b] = wsum[0] + wsum[1] + wsum[2] + wsum[3];
}

__global__ void scan_block_both(int* __restrict__ partH, int nbH,
                                int* __restrict__ partU, int nbU) {
    __shared__ int sh[256];
    int t = threadIdx.x;
    for (int pass = 0; pass < 2; ++pass) {
        int* part = pass ? partU : partH;
        int nb = pass ? nbU : nbH;
        int v = (t < nb) ? part[t] : 0;
        sh[t] = v;
        __syncthreads();
        for (int d = 1; d < 256; d <<= 1) {
            int x = (t >= d) ? sh[t - d] : 0;
            __syncthreads();
            sh[t] += x;
            __syncthreads();
        }
        if (t < nb) part[t] = sh[t] - v; // exclusive
        __syncthreads();
    }
}

// writes both off[] and cur[] (fill cursor)
__global__ void scan_final_both(const int* __restrict__ degH, const int* __restrict__ partH,
                                int* __restrict__ offH, int* __restrict__ curH,
                                int nH, int nbH, int totalH,
                                const int* __restrict__ degU, const int* __restrict__ partU,
                                int* __restrict__ offU, int* __restrict__ curU,
                                int nU, int totalU) {
    bool isU = (int)blockIdx.x >= nbH;
    const int* deg = isU ? degU : degH;
    const int* part = isU ? partU : partH;
    int* off = isU ? offU : offH;
    int* cur = isU ? curU : curH;
    int n = isU ? nU : nH;
    int total = isU ? totalU : totalH;
    int b = isU ? blockIdx.x - nbH : blockIdx.x;
    int t = threadIdx.x;
    int lane = t & 63, w = t >> 6;
    int i0 = b * 1024 + t * 4;
    int v[4]; int s = 0;
#pragma unroll
    for (int k = 0; k < 4; ++k) { int id = i0 + k; v[k] = (id < n) ? deg[id] : 0; s += v[k]; }
    int incl = s;
#pragma unroll
    for (int d = 1; d < 64; d <<= 1) { int x = __shfl_up(incl, d, 64); if (lane >= d) incl += x; }
    __shared__ int wsum[4];
    if (lane == 63) wsum[w] = incl;
    __syncthreads();
    int woff = 0;
    for (int i = 0; i < w; ++i) woff += wsum[i];
    int excl = incl - s + woff + part[b];
#pragma unroll
    for (int k = 0; k < 4; ++k) {
        int id = i0 + k;
        if (id < n) { off[id] = excl; cur[id] = excl; }
        excl += v[k];
    }
    if (b == 0 && t == 0) off[n] = total;
}

// ---------------- partition base cursors from off[] ----------------
__global__ void pcur_init(const int* __restrict__ off_h, int n_ent, int shiftH,
                          int* __restrict__ pcurK,
                          const int* __restrict__ off_u, int n_usr, int shiftU,
                          int* __restrict__ pcurU) {
    int t = threadIdx.x;
    if (t < NPART) {
        pcurK[t] = off_h[min(t << shiftH, n_ent)];
        pcurU[t] = off_u[min(t << shiftU, n_usr)];
    }
}

// ---------------- P3: self-reserving dense bucket write ----------------
__global__ void __launch_bounds__(256) p3_bucket_kernel(
        const int* __restrict__ head, const int* __restrict__ tail,
        const int* __restrict__ etype, int E, int shiftH,
        int* __restrict__ pcurK, uint2* __restrict__ bktK,
        const int* __restrict__ iu, const int* __restrict__ ii,
        const float* __restrict__ w, int EI, int shiftU,
        int* __restrict__ pcurU, uint2* __restrict__ bktU) {
    __shared__ int lc[NPART];
    int b = blockIdx.x;
    if (threadIdx.x < NPART) lc[threadIdx.x] = 0;
    __syncthreads();
    if (b < NBK) {
        int chunk = (E + NBK - 1) / NBK;
        int lo = b * chunk, hi = min(lo + chunk, E);
        for (int e = lo + (int)threadIdx.x; e < hi; e += 256)
            atomicAdd(&lc[head[e] >> shiftH], 1);
        __syncthreads();
        if (threadIdx.x < NPART)
            lc[threadIdx.x] = atomicAdd(&pcurK[threadIdx.x], lc[threadIdx.x]);
        __syncthreads();
        for (int e = lo + (int)threadIdx.x; e < hi; e += 256) {
            int h = head[e];
            int pos = atomicAdd(&lc[h >> shiftH], 1);
            bktK[pos] = make_uint2((unsigned)(tail[e] | ((etype[e] - 1) << 17)), (unsigned)h);
        }
    } else {
        int bb = b - NBK;
        int chunk = (EI + NBU - 1) / NBU;
        int lo = bb * chunk, hi = min(lo + chunk, EI);
        for (int e = lo + (int)threadIdx.x; e < hi; e += 256)
            atomicAdd(&lc[iu[e] >> shiftU], 1);
        __syncthreads();
        if (threadIdx.x < NPART)
            lc[threadIdx.x] = atomicAdd(&pcurU[threadIdx.x], lc[threadIdx.x]);
        __syncthreads();
        for (int e = lo + (int)threadIdx.x; e < hi; e += 256) {
            int u = iu[e];
            int pos = atomicAdd(&lc[u >> shiftU], 1);
            unsigned wq = (unsigned)(w[e] * 32767.f + 0.5f);
            bktU[pos] = make_uint2((unsigned)ii[e] | (wq << 17), (unsigned)u);
        }
    }
}

// ---------------- P4 (partition-local scatter) MERGED with hop-1 proj ----------------
// fill blocks [0,P4T): partition p = blockIdx%32 keeps writes XCD-local; each
// partition's bucket (~1 MB) + col region (~0.4 MB) stays L2-resident.
// proj blocks [P4T, P4T+PROJ_MERGED): grid-stride proj of entity_emb (disjoint data).
__global__ void __launch_bounds__(256) p4_proj_kernel(
        const uint2* __restrict__ bktK, const int* __restrict__ off_h, int n_ent, int shiftH,
        int* __restrict__ cur_h, int* __restrict__ col_h,
        const uint2* __restrict__ bktU, const int* __restrict__ off_u, int n_usr, int shiftU,
        int* __restrict__ cur_u, unsigned* __restrict__ col_ui,
        const float* __restrict__ e_in, const float* __restrict__ W,
        unsigned* __restrict__ packed) {
    __shared__ float Wl[64 * 64];
    int b = blockIdx.x;
    if (b >= P4T) {
        for (int i = threadIdx.x; i < 64 * 64; i += 256) Wl[i] = W[i];
        __syncthreads();
        int lane = threadIdx.x & 63;
        int wid = (b - P4T) * 4 + (threadIdx.x >> 6);
        proj_rows(e_in, Wl, packed, n_ent, wid, PROJ_MERGED * 4, lane);
        return;
    }
    if (b < P4_KG) {
        int p = b & (NPART - 1), s = b >> 5;            // 32 slices per partition
        int st = off_h[min(p << shiftH, n_ent)];
        int en = off_h[min((p + 1) << shiftH, n_ent)];
        long long len = en - st;
        int lo = st + (int)(len * s / 32);
        int hi = st + (int)(len * (s + 1) / 32);
        for (int i = lo + (int)threadIdx.x; i < hi; i += 256) {
            uint2 r = bktK[i];
            int pos = atomicAdd(&cur_h[r.y], 1);
            col_h[pos] = (int)r.x;
        }
    } else {
        int bb = b - P4_KG;
        int p = bb & (NPART - 1), s = bb >> 5;          // 16 slices per partition
        int st = off_u[min(p << shiftU, n_usr)];
        int en = off_u[min((p + 1) << shiftU, n_usr)];
        long long len = en - st;
        int lo = st + (int)(len * s / 16);
        int hi = st + (int)(len * (s + 1) / 16);
        for (int i = lo + (int)threadIdx.x; i < hi; i += 256) {
            uint2 r = bktU[i];
            int pos = atomicAdd(&cur_u[r.y], 1);
            col_ui[pos] = r.x;
        }
    }
}

// ------- fused agg: KG = 2 dims/lane, 2 edges/wave;  UI = per-user weighted agg -------
#define KG_PAIR(J, P, W) {                                                  \
        int rr = (P) >> 17;                                                 \
        float rl0 = relS[rr * EMB + dd], rl1 = relS[rr * EMB + dd + 1];     \
        float pt0 = bfhi(W.x), pt1 = bfhi(W.y);                             \
        float et0 = bflo(W.x), et1 = bflo(W.y);                             \
        float prod = fmaf(q0 * rl0, pt0, q1 * rl1 * pt1);                   \
        prod += __shfl_xor(prod, 1, 64);                                    \
        prod += __shfl_xor(prod, 2, 64);                                    \
        prod += __shfl_xor(prod, 4, 64);                                    \
        prod += __shfl_xor(prod, 8, 64);                                    \
        float ex = __expf(prod * INV_SQRT_DK);                              \
        if ((J) + half >= e) ex = 0.f;                                      \
        den += ex;                                                          \
        num0 = fmaf(ex * rl0, et0, num0);                                   \
        num1 = fmaf(ex * rl1, et1, num1); }

template <bool HOP1>
__global__ void agg_fused_kernel(const unsigned* __restrict__ packed,
                                 const float* __restrict__ rel_emb,
                                 const int* __restrict__ off_h, const int* __restrict__ col_h,
                                 const int* __restrict__ off_u,
                                 const unsigned* __restrict__ col_ui,
                                 const float* __restrict__ e_base, float* __restrict__ e_cur,
                                 float* __restrict__ e_res, int n_ent,
                                 const float* __restrict__ u_base, float* __restrict__ u_res,
                                 int n_usr, int kgBlocks, int totalBlocks) {
    __shared__ float relS[16 * EMB];
    int bid = blockIdx.x;
    // Bresenham interleave of kg-role and ui-role blocks
    size_t lo = (size_t)bid * kgBlocks / totalBlocks;
    size_t hi = (size_t)(bid + 1) * kgBlocks / totalBlocks;
    int lane = threadIdx.x & 63;
    int wslot = threadIdx.x >> 6;

    if (hi > lo) {
        // ---------------- KG entity block: 2 dims/lane, 2 edges/wave ----------------
        for (int i = threadIdx.x; i < 16 * EMB; i += blockDim.x) relS[i] = rel_emb[i];
        __syncthreads();
        int wid = (int)lo * 4 + wslot;
        if (wid >= n_ent) return;
        int s = off_h[wid], e = off_h[wid + 1];
        int half = lane >> 5;
        int sub  = lane & 31;
        int dd   = sub * 2;
        uint2 qw = *(const uint2*)&packed[(size_t)wid * EMB + dd];
        float q0 = bfhi(qw.x), q1 = bfhi(qw.y);
        float num0 = 0.f, num1 = 0.f, den = 0.f;
        int j = s;
        for (; j + 3 < e; j += 4) {           // 2 pairs (4 edges), no dummies possible
            int pA = col_h[j + half];
            int pB = col_h[j + 2 + half];
            uint2 wA = *(const uint2*)&packed[(size_t)(pA & 131071) * EMB + dd];
            uint2 wB = *(const uint2*)&packed[(size_t)(pB & 131071) * EMB + dd];
            KG_PAIR(j, pA, wA);
            KG_PAIR(j + 2, pB, wB);
        }
        for (; j < e; j += 2) {               // remainder pair, may have a dummy lane-half
            int jj = j + half; if (jj >= e) jj = e - 1;
            int pA = col_h[jj];
            uint2 wA = *(const uint2*)&packed[(size_t)(pA & 131071) * EMB + dd];
            KG_PAIR(j, pA, wA);
        }
        // combine the two edge-halves (once per node)
        den  += __shfl_xor(den, 32, 64);
        num0 += __shfl_xor(num0, 32, 64);
        num1 += __shfl_xor(num1, 32, 64);
        float inv = (e > s) ? 1.f / den : 0.f;   // deferred softmax division
        float v0 = num0 * inv, v1 = num1 * inv;
        float ss = fmaf(v0, v0, v1 * v1);
#pragma unroll
        for (int m = 1; m <= 16; m <<= 1) ss += __shfl_xor(ss, m, 64);
        float rn = 1.f / fmaxf(sqrtf(ss), 1e-12f);
        float o0 = v0 * rn, o1 = v1 * rn;
        if (half == 0) {
            float2* res2 = (float2*)&e_res[(size_t)wid * EMB + dd];
            if (HOP1) {
                *(float2*)&e_cur[(size_t)wid * EMB + dd] = make_float2(o0, o1);
                const float2 b = *(const float2*)&e_base[(size_t)wid * EMB + dd];
                *res2 = make_float2(b.x + o0, b.y + o1);
            } else {
                float2 rv = *res2;
                *res2 = make_float2(rv.x + o0, rv.y + o1);
            }
        }
    } else {
        // ---------------- UI user block (values from bflo(packed)) ----------------
        int wid = (bid - (int)lo) * 4 + wslot;
        if (wid >= n_usr) return;
        int s = off_u[wid], e = off_u[wid + 1];
        float acc = 0.f;
        int j = s;
        for (; j + 3 < e; j += 4) {
            unsigned c0 = col_ui[j],     c1 = col_ui[j + 1];
            unsigned c2 = col_ui[j + 2], c3 = col_ui[j + 3];
            float w0 = (c0 >> 17) * (1.f / 32767.f);
            float w1 = (c1 >> 17) * (1.f / 32767.f);
            float w2 = (c2 >> 17) * (1.f / 32767.f);
            float w3 = (c3 >> 17) * (1.f / 32767.f);
            float v0 = bflo(packed[(size_t)(c0 & 131071u) * EMB + lane]);
            float v1 = bflo(packed[(size_t)(c1 & 131071u) * EMB + lane]);
            float v2 = bflo(packed[(size_t)(c2 & 131071u) * EMB + lane]);
            float v3 = bflo(packed[(size_t)(c3 & 131071u) * EMB + lane]);
            acc = fmaf(w0, v0, acc);
            acc = fmaf(w1, v1, acc);
            acc = fmaf(w2, v2, acc);
            acc = fmaf(w3, v3, acc);
        }
        for (; j < e; ++j) {
            unsigned c = col_ui[j];
            acc = fmaf((c >> 17) * (1.f / 32767.f),
                       bflo(packed[(size_t)(c & 131071u) * EMB + lane]), acc);
        }
        float ss = acc * acc;
#pragma unroll
        for (int m = 1; m <= 32; m <<= 1) ss += __shfl_xor(ss, m, 64);
        float o = acc / fmaxf(sqrtf(ss), 1e-12f);
        size_t ix = (size_t)wid * EMB + lane;
        if (HOP1) u_res[ix] = u_base[ix] + o;
        else      u_res[ix] += o;
    }
}

extern "C" void kernel_launch(void* const* d_in, const int* in_sizes, int n_in,
                              void* d_out, int out_size, void* d_ws, size_t ws_size,
                              hipStream_t stream) {
    const float* user_emb   = (const float*)d_in[0];
    const float* entity_emb = (const float*)d_in[1];
    const int*   edge_index = (const int*)d_in[2];   // [2, E]
    const int*   edge_type  = (const int*)d_in[3];   // [E]
    const int*   inter_edge = (const int*)d_in[4];   // [2, EI]
    const float* inter_w    = (const float*)d_in[5]; // [EI]
    const float* W_Q        = (const float*)d_in[6]; // [64,64]
    const float* rel_emb    = (const float*)d_in[7]; // [16,64]

    const int E     = in_sizes[3];
    const int EI    = in_sizes[5];
    const int n_ent = in_sizes[1] / EMB;
    const int n_usr = in_sizes[0] / EMB;

    const int* head = edge_index;
    const int* tail = edge_index + E;
    const int* iu   = inter_edge;
    const int* ii   = inter_edge + EI;

    // partition shifts: smallest shift with <= NPART partitions
    int shiftH = 0; while (((n_ent + (1 << shiftH) - 1) >> shiftH) > NPART) ++shiftH;
    int shiftU = 0; while (((n_usr + (1 << shiftU) - 1) >> shiftU) > NPART) ++shiftU;

    // ---- workspace layout ----
    char* ws = (char*)d_ws;
    unsigned* packed = (unsigned*)ws;          ws += (size_t)n_ent * EMB * 4;
    float* e_cur = (float*)ws;                 ws += (size_t)n_ent * EMB * 4;
    int*      col_h  = (int*)ws;               ws += (size_t)E * 4;
    unsigned* col_ui = (unsigned*)ws;          ws += (size_t)EI * 4;
    int*   off_h = (int*)ws;                   ws += (size_t)(n_ent + 1) * 4;
    int*   off_u = (int*)ws;                   ws += (size_t)(n_usr + 1) * 4;
    int*   cur_h = (int*)ws;                   ws += (size_t)n_ent * 4;   // cur_h|cur_u adjacent
    int*   cur_u = (int*)ws;                   ws += (size_t)n_usr * 4;
    int*   partH = (int*)ws;                   ws += 256 * 4;
    int*   partU = (int*)ws;                   ws += 256 * 4;
    int*   pcurK = (int*)ws;                   ws += NPART * 4;
    int*   pcurU = (int*)ws;                   ws += NPART * 4;
    // buckets overlay e_cur (dead until hop-1 agg writes it, after p4)
    uint2* bktK = (uint2*)e_cur;               // E * 8 bytes
    uint2* bktU = bktK + E;                    // EI * 8 bytes (24 MB <= 25.6 MB region)

    float* e_res = (float*)d_out;
    float* u_res = e_res + (size_t)n_ent * EMB;

    const int nbH = (n_ent + 1023) / 1024;     // 98  (<=256)
    const int nbU = (n_usr + 1023) / 1024;     // 49  (<=256)

    // ---- CSR build via partition counting-sort (reused by both hops) ----
    hipMemsetAsync(cur_h, 0, (size_t)(n_ent + n_usr) * 4, stream);
    p1_hist<<<(E + EI + 255) / 256, 256, 0, stream>>>(head, cur_h, E, iu, cur_u, EI);
    scan_partial_both<<<nbH + nbU, 256, 0, stream>>>(cur_h, partH, n_ent, nbH, cur_u, partU, n_usr);
    scan_block_both<<<1, 256, 0, stream>>>(partH, nbH, partU, nbU);
    scan_final_both<<<nbH + nbU, 256, 0, stream>>>(cur_h, partH, off_h, cur_h, n_ent, nbH, E,
                                                   cur_u, partU, off_u, cur_u, n_usr, EI);
    pcur_init<<<1, 64, 0, stream>>>(off_h, n_ent, shiftH, pcurK, off_u, n_usr, shiftU, pcurU);
    p3_bucket_kernel<<<NBK + NBU, 256, 0, stream>>>(head, tail, edge_type, E, shiftH, pcurK, bktK,
                                                    iu, ii, inter_w, EI, shiftU, pcurU, bktU);
    // p4 scatter + hop-1 proj merged (disjoint data; fill blocks first for XCD alignment)
    p4_proj_kernel<<<P4T + PROJ_MERGED, 256, 0, stream>>>(
        bktK, off_h, n_ent, shiftH, cur_h, col_h,
        bktU, off_u, n_usr, shiftU, cur_u, col_ui,
        entity_emb, W_Q, packed);

    const int kgBlocks = (n_ent + 3) / 4;
    const int uiBlocks = (n_usr + 3) / 4;
    const int totalBlocks = kgBlocks + uiBlocks;

    // ---- hop 1 (e_in = entity_emb) ----
    agg_fused_kernel<true><<<totalBlocks, 256, 0, stream>>>(
        packed, rel_emb, off_h, col_h, off_u, col_ui,
        entity_emb, e_cur, e_res, n_ent, user_emb, u_res, n_usr, kgBlocks, totalBlocks);

    // ---- hop 2 (e_in = e_cur) ----
    proj_pack_kernel<<<PROJ2_BLOCKS, 256, 0, stream>>>(e_cur, W_Q, packed, n_ent);
    agg_fused_kernel<false><<<totalBlocks, 256, 0, stream>>>(
        packed, rel_emb, off_h, col_h, off_u, col_ui,
        nullptr, nullptr, e_res, n_ent, nullptr, u_res, n_usr, kgBlocks, totalBlocks);
}